// Round 9
// baseline (617.766 us; speedup 1.0000x reference)
//
#include <hip/hip_runtime.h>
#include <math.h>

// FusionEncoder: E=1024, F=4096, N=64 docs, L=2 layers, fp32.
// R9: multi-kernel (graph kernel-boundary = cheapest global barrier, ~6us vs
// ~18us for in-kernel agent-scope barriers, R8) + DETERMINISTIC split-K via
// int64 fixed-point atomicAdd (integer add commutes -> replay-identical,
// unlike R7's fp32 atomics). All reduce dispatches eliminated: epilogues
// fuse into consumer A-loads. 19 dispatches, ~60MB partial traffic removed.

#define EDIM 1024
#define FDIM 4096

typedef long long ll;
typedef unsigned long long ull;
#define SCALE_D  1099511627776.0          // 2^40
#define INV_SCALE 9.094947017729282e-13   // 2^-40

__device__ __forceinline__ float i2f(ll v) {
  return (float)((double)v * INV_SCALE);
}
__device__ __forceinline__ void atomg(ull* p, float v) {
  atomicAdd(p, (ull)__double2ll_rn((double)v * SCALE_D));
}

// ---------------- block-wide sum over 256 threads (4 waves) ----------------
__device__ __forceinline__ float block_sum256(float v) {
  __shared__ float lds[4];
  #pragma unroll
  for (int off = 32; off; off >>= 1) v += __shfl_down(v, off);
  const int wid  = threadIdx.x >> 6;
  const int lane = threadIdx.x & 63;
  __syncthreads();
  if (lane == 0) lds[wid] = v;
  __syncthreads();
  return lds[0] + lds[1] + lds[2] + lds[3];
}

#define FMA4(ACC, S, W4) \
  ACC.x = fmaf(S, W4.x, ACC.x); ACC.y = fmaf(S, W4.y, ACC.y); \
  ACC.z = fmaf(S, W4.z, ACC.z); ACC.w = fmaf(S, W4.w, ACC.w);

// ---- skinny GEMM, 64x64 tile, K-slice [kb,kb+Kt); A & W staged in LDS ------
// MODE_A: 0 = plain float A; 1 = concat(q,doc); 2 = i64 acc + bias;
//         3 = relu(i64 acc + bias). Output: int64 fixed-point atomicAdd.
template<int MODE_A>
__global__ __launch_bounds__(256)
void gemm_k(const float* __restrict__ Af, int lda_f,
            const ll* __restrict__ Ai, int lda_i,
            const float* __restrict__ abias,
            const float* __restrict__ qv, const float* __restrict__ doc,
            const float* __restrict__ W, int ldw,
            ull* __restrict__ Acc, int Nout, int Kt)
{
  __shared__ float As[64 * 68];
  __shared__ float Ws[64 * 68];
  const int t   = threadIdx.x;
  const int cgi = t & 15;
  const int r0  = (t >> 4) * 4;
  const int jb  = blockIdx.x * 64;
  const int jc  = jb + cgi * 4;
  const int kb  = blockIdx.y * Kt;

  float4 acc[4];
  #pragma unroll
  for (int i = 0; i < 4; ++i) acc[i] = make_float4(0.f, 0.f, 0.f, 0.f);

  for (int k0 = kb; k0 < kb + Kt; k0 += 64) {
    __syncthreads();
    #pragma unroll
    for (int it = 0; it < 4; ++it) {               // stage A[0..63][k0+0..63]
      const int pi  = t + it * 256;
      const int row = pi >> 4;
      const int c4  = (pi & 15) * 4;
      const int k   = k0 + c4;
      float4 val;
      if (MODE_A == 0) {
        val = *(const float4*)(Af + (size_t)row * lda_f + k);
      } else if (MODE_A == 1) {
        val = (k < EDIM) ? *(const float4*)(qv + k)
                         : *(const float4*)(doc + (size_t)row * EDIM + (k - EDIM));
      } else {
        const ll* ap = Ai + (size_t)row * lda_i + k;
        const float4 b4 = *(const float4*)(abias + k);
        val.x = i2f(ap[0]) + b4.x; val.y = i2f(ap[1]) + b4.y;
        val.z = i2f(ap[2]) + b4.z; val.w = i2f(ap[3]) + b4.w;
        if (MODE_A == 3) {
          val.x = fmaxf(val.x, 0.f); val.y = fmaxf(val.y, 0.f);
          val.z = fmaxf(val.z, 0.f); val.w = fmaxf(val.w, 0.f);
        }
      }
      *(float4*)(As + row * 68 + c4) = val;
    }
    #pragma unroll
    for (int it = 0; it < 4; ++it) {               // stage W[k0+0..63][jb+0..63]
      const int pi  = t + it * 256;
      const int row = pi >> 4;
      const int c4  = (pi & 15) * 4;
      *(float4*)(Ws + row * 68 + c4) =
          *(const float4*)(W + (size_t)(k0 + row) * ldw + jb + c4);
    }
    __syncthreads();
    #pragma unroll 4
    for (int kk4 = 0; kk4 < 64; kk4 += 4) {
      const float4 a0 = *(const float4*)(As + (r0 + 0) * 68 + kk4);
      const float4 a1 = *(const float4*)(As + (r0 + 1) * 68 + kk4);
      const float4 a2 = *(const float4*)(As + (r0 + 2) * 68 + kk4);
      const float4 a3 = *(const float4*)(As + (r0 + 3) * 68 + kk4);
      const float4 w0 = *(const float4*)(Ws + (kk4 + 0) * 68 + cgi * 4);
      const float4 w1 = *(const float4*)(Ws + (kk4 + 1) * 68 + cgi * 4);
      const float4 w2 = *(const float4*)(Ws + (kk4 + 2) * 68 + cgi * 4);
      const float4 w3 = *(const float4*)(Ws + (kk4 + 3) * 68 + cgi * 4);
      FMA4(acc[0], a0.x, w0) FMA4(acc[0], a0.y, w1) FMA4(acc[0], a0.z, w2) FMA4(acc[0], a0.w, w3)
      FMA4(acc[1], a1.x, w0) FMA4(acc[1], a1.y, w1) FMA4(acc[1], a1.z, w2) FMA4(acc[1], a1.w, w3)
      FMA4(acc[2], a2.x, w0) FMA4(acc[2], a2.y, w1) FMA4(acc[2], a2.z, w2) FMA4(acc[2], a2.w, w3)
      FMA4(acc[3], a3.x, w0) FMA4(acc[3], a3.y, w1) FMA4(acc[3], a3.z, w2) FMA4(acc[3], a3.w, w3)
    }
  }
  #pragma unroll
  for (int i = 0; i < 4; ++i) {
    ull* d = Acc + (size_t)(r0 + i) * Nout + jc;
    atomg(d + 0, acc[i].x); atomg(d + 1, acc[i].y);
    atomg(d + 2, acc[i].z); atomg(d + 3, acc[i].w);
  }
}

// ---- LayerNorm: out = LN(res + cvt(acc)+bias); res float or i64+bias -------
template<int RESI>
__global__ __launch_bounds__(256)
void ln_k(const ll* __restrict__ acc, const float* __restrict__ bias,
          const float* __restrict__ resf,
          const ll* __restrict__ resi, const float* __restrict__ rbias,
          const float* __restrict__ gam, const float* __restrict__ bet,
          float* __restrict__ outp)
{
  const int row = blockIdx.x;
  const int c   = threadIdx.x * 4;
  const ll* ap = acc + (size_t)row * EDIM + c;
  const float4 b4 = *(const float4*)(bias + c);
  float4 v;
  v.x = i2f(ap[0]) + b4.x; v.y = i2f(ap[1]) + b4.y;
  v.z = i2f(ap[2]) + b4.z; v.w = i2f(ap[3]) + b4.w;
  if (RESI) {
    const ll* rp = resi + (size_t)row * EDIM + c;
    const float4 rb = *(const float4*)(rbias + c);
    v.x += i2f(rp[0]) + rb.x; v.y += i2f(rp[1]) + rb.y;
    v.z += i2f(rp[2]) + rb.z; v.w += i2f(rp[3]) + rb.w;
  } else {
    const float4 r4 = *(const float4*)(resf + (size_t)row * EDIM + c);
    v.x += r4.x; v.y += r4.y; v.z += r4.z; v.w += r4.w;
  }
  const float mean = block_sum256(v.x + v.y + v.z + v.w) * (1.f / 1024.f);
  const float dx = v.x - mean, dy = v.y - mean, dz = v.z - mean, dw = v.w - mean;
  const float var = block_sum256(dx * dx + dy * dy + dz * dz + dw * dw) * (1.f / 1024.f);
  const float inv = 1.f / sqrtf(var + 1e-5f);
  const float4 g4 = *(const float4*)(gam + c);
  const float4 l4 = *(const float4*)(bet + c);
  float4 o;
  o.x = dx * inv * g4.x + l4.x; o.y = dy * inv * g4.y + l4.y;
  o.z = dz * inv * g4.z + l4.z; o.w = dw * inv * g4.w + l4.w;
  *(float4*)(outp + (size_t)row * EDIM + c) = o;
}

// ---- logits[row] = relu(cvt(wa1acc)+ba1) . Wa2 + ba2 ; 64 blocks -----------
__global__ __launch_bounds__(256)
void logits_k(const ll* __restrict__ wa1acc, const float* __restrict__ ba1,
              const float* __restrict__ Wa2, const float* __restrict__ ba2,
              float* __restrict__ logits)
{
  const int row = blockIdx.x;
  const int t   = threadIdx.x;
  float dot = 0.f;
  #pragma unroll
  for (int i = 0; i < 4; ++i) {
    const int col = (t + i * 256) * 4;
    const ll* ap = wa1acc + (size_t)row * FDIM + col;
    const float4 b4 = *(const float4*)(ba1 + col);
    float4 v;
    v.x = fmaxf(i2f(ap[0]) + b4.x, 0.f); v.y = fmaxf(i2f(ap[1]) + b4.y, 0.f);
    v.z = fmaxf(i2f(ap[2]) + b4.z, 0.f); v.w = fmaxf(i2f(ap[3]) + b4.w, 0.f);
    const float4 w2 = *(const float4*)(Wa2 + col);
    dot = fmaf(v.x, w2.x, fmaf(v.y, w2.y, fmaf(v.z, w2.z, fmaf(v.w, w2.w, dot))));
  }
  const float s = block_sum256(dot);
  if (t == 0) logits[row] = s + ba2[0];
}

// ---- softmax over 64 + weighted pool; block 0 writes w ---------------------
__global__ __launch_bounds__(256)
void pool_k(const float* __restrict__ logits, const float* __restrict__ x,
            float* __restrict__ fused, float* __restrict__ w_out)
{
  __shared__ float llv[64];
  __shared__ float wl[64];
  const int t = threadIdx.x;
  if (t < 64) llv[t] = logits[t];
  __syncthreads();
  float m = -1e30f;
  for (int i = 0; i < 64; ++i) m = fmaxf(m, llv[i]);
  float den = 0.f;
  for (int i = 0; i < 64; ++i) den += expf(llv[i] - m);
  if (t < 64) wl[t] = expf(llv[t] - m) / den;
  __syncthreads();
  const int j = blockIdx.x * 256 + t;
  float acc = 0.f;
  for (int i = 0; i < 64; ++i) acc = fmaf(wl[i], x[(size_t)i * EDIM + j], acc);
  fused[j] = acc;
  if (blockIdx.x == 0 && t < 64) w_out[t] = wl[t];
}

// ---- gemv1: gacc += fused @ Wf1 chunk  (grid 16 x 32, Kt=32) ---------------
__global__ __launch_bounds__(256)
void gemv1_k(const float* __restrict__ fused, const float* __restrict__ Wf1,
             ull* __restrict__ gacc)
{
  __shared__ float vl[32];
  const int t  = threadIdx.x;
  const int k0 = blockIdx.y * 32;
  if (t < 32) vl[t] = fused[k0 + t];
  __syncthreads();
  const int col = blockIdx.x * 256 + t;
  const float* wp = Wf1 + (size_t)k0 * FDIM + col;
  float acc = 0.f;
  #pragma unroll
  for (int kk = 0; kk < 32; ++kk) acc = fmaf(vl[kk], wp[(size_t)kk * FDIM], acc);
  atomg(gacc + col, acc);
}

// ---- gemv2: f2acc += relu(cvt(gacc)+bf1) @ Wf2 chunk  (grid 16 x 32, Kt=128)
__global__ __launch_bounds__(256)
void gemv2_k(const ll* __restrict__ gacc, const float* __restrict__ bf1,
             const float* __restrict__ Wf2, ull* __restrict__ f2acc)
{
  __shared__ float vl[128];
  const int t  = threadIdx.x;
  const int k0 = blockIdx.y * 128;
  if (t < 128) vl[t] = fmaxf(i2f(gacc[k0 + t]) + bf1[k0 + t], 0.f);
  __syncthreads();
  const int col = blockIdx.x * 256 + t;
  const float* wp = Wf2 + (size_t)k0 * FDIM + col;
  float acc = 0.f;
  #pragma unroll 16
  for (int kk = 0; kk < 128; ++kk) acc = fmaf(vl[kk], wp[(size_t)kk * FDIM], acc);
  atomg(f2acc + col, acc);
}

// ---- final: out[j] = cvt(f2acc)+bf2 ; 16 blocks ----------------------------
__global__ __launch_bounds__(256)
void final_k(const ll* __restrict__ f2acc, const float* __restrict__ bf2,
             float* __restrict__ out)
{
  const int j = blockIdx.x * 256 + threadIdx.x;
  out[j] = i2f(f2acc[j]) + bf2[j];
}

// ---------------------------------------------------------------------------
extern "C" void kernel_launch(void* const* d_in, const int* in_sizes, int n_in,
                              void* d_out, int out_size, void* d_ws, size_t ws_size,
                              hipStream_t stream) {
  (void)in_sizes; (void)n_in; (void)out_size; (void)ws_size;
  const float* q    = (const float*)d_in[0];
  const float* doc  = (const float*)d_in[1];
  const float* Wp   = (const float*)d_in[2];
  const float* bp   = (const float*)d_in[3];
  const float* Wqkv = (const float*)d_in[4];
  const float* bqkv = (const float*)d_in[5];
  const float* Wo   = (const float*)d_in[6];
  const float* bo   = (const float*)d_in[7];
  const float* ln1g = (const float*)d_in[8];
  const float* ln1b = (const float*)d_in[9];
  const float* ln2g = (const float*)d_in[10];
  const float* ln2b = (const float*)d_in[11];
  const float* W1   = (const float*)d_in[12];
  const float* b1   = (const float*)d_in[13];
  const float* W2   = (const float*)d_in[14];
  const float* b2   = (const float*)d_in[15];
  const float* Wa1  = (const float*)d_in[16];
  const float* ba1  = (const float*)d_in[17];
  const float* Wa2  = (const float*)d_in[18];
  const float* ba2  = (const float*)d_in[19];
  const float* Wf1  = (const float*)d_in[20];
  const float* bf1  = (const float*)d_in[21];
  const float* Wf2  = (const float*)d_in[22];
  const float* bf2  = (const float*)d_in[23];
  float* out = (float*)d_out;

  // --- workspace: int64 accumulators first (8B-aligned), floats after ------
  ll*  ab = (ll*)d_ws;
  ll* projacc = ab;                    // 64x1024
  ll* vacc    = ab + 65536;            // 2 x 64x1024
  ll* attnacc = ab + 196608;           // 2 x 64x1024
  ll* ffn1acc = ab + 327680;           // 2 x 64x4096
  ll* ffn2acc = ab + 851968;           // 2 x 64x1024
  ll* wa1acc  = ab + 983040;           // 64x4096
  ll* gacc    = ab + 1245184;          // 4096
  ll* f2acc   = ab + 1249280;          // 4096
  const size_t accll = 1253376;        // total i64 count
  float* fb    = (float*)(ab + accll);
  float* xbuf  = fb;                   // 64x1024
  float* fused = fb + 65536;           // 1024
  float* logit = fb + 66560;           // 64

  const dim3 blk(256);

  // zero all accumulators (deterministic start each call)
  (void)hipMemsetAsync(ab, 0, accll * 8, stream);

  // proj: projacc += concat(q,doc) @ Wp    (grid 16x32, Kt=64, K=2048)
  gemm_k<1><<<dim3(16,32), blk, 0, stream>>>(nullptr, 0, nullptr, 0, nullptr,
      q, doc, Wp, EDIM, (ull*)projacc, EDIM, 64);

  for (int l = 0; l < 2; ++l) {
    const float* Wv  = Wqkv + (size_t)l * EDIM * 3 * EDIM + 2 * EDIM;
    const float* bv  = bqkv + l * 3 * EDIM + 2 * EDIM;
    const float* Wol = Wo + (size_t)l * EDIM * EDIM;
    const float* W1l = W1 + (size_t)l * EDIM * FDIM;
    const float* W2l = W2 + (size_t)l * FDIM * EDIM;
    ll* vacc_l    = vacc    + (size_t)l * 65536;
    ll* attnacc_l = attnacc + (size_t)l * 65536;
    ll* ffn1acc_l = ffn1acc + (size_t)l * 262144;
    ll* ffn2acc_l = ffn2acc + (size_t)l * 65536;

    // v = x @ Wv ; layer0 A = cvt(projacc)+bp (MODE2), layer1 A = xbuf (MODE0)
    if (l == 0)
      gemm_k<2><<<dim3(16,16), blk, 0, stream>>>(nullptr, 0, projacc, EDIM, bp,
          nullptr, nullptr, Wv, 3 * EDIM, (ull*)vacc_l, EDIM, 64);
    else
      gemm_k<0><<<dim3(16,16), blk, 0, stream>>>(xbuf, EDIM, nullptr, 0, nullptr,
          nullptr, nullptr, Wv, 3 * EDIM, (ull*)vacc_l, EDIM, 64);

    // attn = v @ Wo ; A = cvt(vacc)+bv (MODE2)
    gemm_k<2><<<dim3(16,16), blk, 0, stream>>>(nullptr, 0, vacc_l, EDIM, bv,
        nullptr, nullptr, Wol, EDIM, (ull*)attnacc_l, EDIM, 64);

    // x = LN1(x + attn + bo)
    if (l == 0)
      ln_k<1><<<64, blk, 0, stream>>>(attnacc_l, bo + l * EDIM, nullptr,
          projacc, bp, ln1g + l * EDIM, ln1b + l * EDIM, xbuf);
    else
      ln_k<0><<<64, blk, 0, stream>>>(attnacc_l, bo + l * EDIM, xbuf,
          nullptr, nullptr, ln1g + l * EDIM, ln1b + l * EDIM, xbuf);

    // ffn1: ffn1acc += x @ W1   (grid 64x8, Kt=128)
    gemm_k<0><<<dim3(64,8), blk, 0, stream>>>(xbuf, EDIM, nullptr, 0, nullptr,
        nullptr, nullptr, W1l, FDIM, (ull*)ffn1acc_l, FDIM, 128);

    // ffn2: ffn2acc += relu(cvt(ffn1acc)+b1) @ W2   (grid 16x32, Kt=128)
    gemm_k<3><<<dim3(16,32), blk, 0, stream>>>(nullptr, 0, ffn1acc_l, FDIM,
        b1 + (size_t)l * FDIM, nullptr, nullptr, W2l, EDIM, (ull*)ffn2acc_l, EDIM, 128);

    // x = LN2(x + ffn2 + b2)
    ln_k<0><<<64, blk, 0, stream>>>(ffn2acc_l, b2 + l * EDIM, xbuf,
        nullptr, nullptr, ln2g + l * EDIM, ln2b + l * EDIM, xbuf);
  }

  // wa1: wa1acc += x @ Wa1   (grid 64x8, Kt=128)
  gemm_k<0><<<dim3(64,8), blk, 0, stream>>>(xbuf, EDIM, nullptr, 0, nullptr,
      nullptr, nullptr, Wa1, FDIM, (ull*)wa1acc, FDIM, 128);

  // logits, softmax+pool
  logits_k<<<64, blk, 0, stream>>>(wa1acc, ba1, Wa2, ba2, logit);
  pool_k<<<4, blk, 0, stream>>>(logit, xbuf, fused, out + FDIM);

  // head GEMVs
  gemv1_k<<<dim3(16,32), blk, 0, stream>>>(fused, Wf1, (ull*)gacc);
  gemv2_k<<<dim3(16,32), blk, 0, stream>>>(gacc, bf1, Wf2, (ull*)f2acc);
  final_k<<<16, blk, 0, stream>>>(f2acc, bf2, out);
}